// Round 11
// baseline (1139.762 us; speedup 1.0000x reference)
//
#include <hip/hip_runtime.h>
#include <stdint.h>
#include <math.h>

// Round 17.
// r16 counters: fold_g 565us VALUBusy 67% = VALU-ISSUE-BOUND at ~3.7
// instr/gather (2 readlane + addr + fma); FETCH 247MB (L2/L3 residency
// CONFIRMED), WRITE 263MB (amplification FIXED). select inferred ~435us
// (unexplained, needs counters).
// fold v6: amortize overhead over 2 rows/lane:
//  - lane owns rows (2lane, 2lane+1): one global_load_dwordx2 per entry
//    feeds 2 fmas. Pair stream via UNIFORM SCALAR loads (safe now: gathers
//    are vmcnt; lgkmcnt has only s_loads; 4 waves/SIMD hide chunk latency).
//  - k pre-scaled to xTg BYTE offset in fillA (k<<16).
//  - per entry: v_add + loadx2 + 2 fma = 3 VALU / 2 outputs (was 3.7 / 1).
//  - block = 128 rows x 2048 cols, 16 waves, grid 256 = full chip;
//    __launch_bounds__(1024,4) pins VGPR<=128.
// select: v5 + 4-way cc chains (break 64-deep dependent add chain); kept
// otherwise so it finally lands in top-5 with counters.
// Numerics unchanged (validated): ascending-k f32 fmaf fold from +0
// (zero-pad exact no-op), +bias, *boost, monotone-u32 key, ties >=.

#define BATCH 16384
#define K_DIM 512
#define N_DIM 4096
#define MAXE 64
#define ROWS_B 128   // rows per fold block (2 per lane)

typedef float f32x4 __attribute__((ext_vector_type(4)));
typedef float f32x2 __attribute__((ext_vector_type(2)));
typedef unsigned int u32;

// ---------- boost table ----------
__global__ void boost_kernel(const float* __restrict__ duty,
                             const int* __restrict__ kptr,
                             float* __restrict__ boost) {
  const int j = blockIdx.x * blockDim.x + threadIdx.x;
  if (j < N_DIM) {
    const float td = (float)((double)kptr[0] / (double)N_DIM);
    const float arg = 0.5f * (td - duty[j]);      // f32 ops, as reference
    boost[j] = (float)exp((double)arg);           // correctly-rounded f32 exp
  }
}

// ---------- compress: per-column nonzeros, ascending k ----------
__global__ __launch_bounds__(256) void compress_kernel(
    const float* __restrict__ W, const float* __restrict__ mask,
    unsigned short* __restrict__ cIdx, float* __restrict__ cVal,
    int* __restrict__ cnt) {
  const int j = blockIdx.x * 4 + (threadIdx.x >> 6);  // one wave per column
  const int lane = threadIdx.x & 63;
  if (j >= N_DIM) return;
  const float* mr = mask + (size_t)j * K_DIM;
  const float* wr = W + (size_t)j * K_DIM;
  int base = 0;
#pragma unroll
  for (int c = 0; c < K_DIM / 64; ++c) {
    const int k = c * 64 + lane;
    const bool act = (mr[k] != 0.0f);
    const unsigned long long bal = __ballot(act);
    const int pos = __popcll(bal & ((1ull << lane) - 1ull));
    if (act && base + pos < MAXE) {
      cIdx[(size_t)j * MAXE + base + pos] = (unsigned short)k;
      cVal[(size_t)j * MAXE + base + pos] = wr[k];   // mask==1 -> exact
    }
    base += (int)__popcll(bal);
  }
  if (lane == 0) cnt[j] = base < MAXE ? base : MAXE;
}

// ---------- per-4-col max count, rounded up to 4 ----------
__global__ __launch_bounds__(256) void cmax_kernel(
    const int* __restrict__ cnt, int* __restrict__ cm4) {
  const int i = blockIdx.x * 256 + threadIdx.x;    // 0..1023
  const int4 c = *(const int4*)(cnt + i * 4);
  int m = c.x > c.y ? c.x : c.y;
  m = c.z > m ? c.z : m;
  m = c.w > m ? c.w : m;
  cm4[i] = (m + 3) & ~3;
}

// ---------- pack (xTg byte-offset, w-bits) pairs, zero-padded ----------
__global__ __launch_bounds__(256) void fillA_kernel(
    const unsigned short* __restrict__ cIdx, const float* __restrict__ cVal,
    const int* __restrict__ cnt, uint2* __restrict__ pairsA) {
  const int idx = blockIdx.x * 256 + threadIdx.x;  // 0 .. 4096*64-1
  const int j = idx >> 6;
  const int e = idx & 63;
  uint2 pr;
  if (e < cnt[j]) {
    pr.x = (u32)cIdx[(size_t)j * MAXE + e] << 16;  // k*16384rows*4B
    pr.y = __float_as_uint(cVal[(size_t)j * MAXE + e]);
  } else {
    pr.x = 0u; pr.y = 0u;                          // exact fold no-op
  }
  pairsA[idx] = pr;
}

// ---------- transpose: x[B][K] -> xTg[K][B] ----------
__global__ __launch_bounds__(256) void transpose_kernel(
    const float* __restrict__ x, float* __restrict__ xTg) {
  __shared__ float t[64][65];
  const int lane = threadIdx.x & 63;
  const int quad = threadIdx.x >> 6;               // 0..3
  const int kb = (blockIdx.x & 7) * 64;            // 8 k-tiles
  const int rb = (blockIdx.x >> 3) * 64;           // 256 row-tiles
#pragma unroll
  for (int i = 0; i < 16; ++i) {
    const int r = quad * 16 + i;
    t[lane][r] = x[(size_t)(rb + r) * K_DIM + kb + lane];  // coalesced read
  }
  __syncthreads();
#pragma unroll
  for (int i = 0; i < 16; ++i) {
    const int kq = quad * 16 + i;
    xTg[(size_t)(kb + kq) * BATCH + rb + lane] = t[kq][lane]; // coalesced write
  }
}

// ---------- fold v6: 2 rows/lane, scalar pair stream, global gather ----------
__global__ __launch_bounds__(1024, 4) void fold_kernel(
    const float* __restrict__ xTg, const uint2* __restrict__ pairsA,
    const int* __restrict__ cm4, float* __restrict__ y) {
  const int tid = threadIdx.x;
  const int lane = tid & 63;
  const int wave = __builtin_amdgcn_readfirstlane(tid >> 6);  // 0..15 uniform
  const int row0 = (blockIdx.x >> 1) * ROWS_B;
  const int colbase = (blockIdx.x & 1) * 2048 + wave * 128;   // uniform
  const char* xb = (const char*)(xTg + row0);      // + kbyte + lane*8
  const u32 vb = (u32)(lane << 3);                 // row-pair byte offset

#pragma unroll 1
  for (int g = 0; g < 4; ++g) {                    // 4 groups of 32 cols
    float accA[32], accB[32];                      // rows 2lane / 2lane+1
#pragma unroll
    for (int q = 0; q < 32; ++q) { accA[q] = 0.0f; accB[q] = 0.0f; }

#pragma unroll
    for (int sub = 0; sub < 8; ++sub) {            // static: 8 subgrp x 4 cols
      const int j0 = colbase + g * 32 + sub * 4;   // uniform
      const int cmax = cm4[j0 >> 2];               // uniform s_load, mult of 4
      const uint2* p0 = pairsA + (size_t)(j0 + 0) * MAXE;
      const uint2* p1 = pairsA + (size_t)(j0 + 1) * MAXE;
      const uint2* p2 = pairsA + (size_t)(j0 + 2) * MAXE;
      const uint2* p3 = pairsA + (size_t)(j0 + 3) * MAXE;
      float a0A = 0.0f, a1A = 0.0f, a2A = 0.0f, a3A = 0.0f;
      float a0B = 0.0f, a1B = 0.0f, a2B = 0.0f, a3B = 0.0f;
#pragma unroll 1
      for (int e = 0; e < cmax; e += 4) {
#pragma unroll
        for (int q = 0; q < 4; ++q) {              // 16 gathers in flight
          const uint2 e0 = p0[e + q];              // uniform -> s_load
          const uint2 e1 = p1[e + q];
          const uint2 e2 = p2[e + q];
          const uint2 e3 = p3[e + q];
          const f32x2 x0 = *(const f32x2*)(xb + (e0.x + vb));
          const f32x2 x1 = *(const f32x2*)(xb + (e1.x + vb));
          const f32x2 x2 = *(const f32x2*)(xb + (e2.x + vb));
          const f32x2 x3 = *(const f32x2*)(xb + (e3.x + vb));
          const float w0 = __uint_as_float(e0.y);
          const float w1 = __uint_as_float(e1.y);
          const float w2 = __uint_as_float(e2.y);
          const float w3 = __uint_as_float(e3.y);
          a0A = fmaf(w0, x0[0], a0A); a0B = fmaf(w0, x0[1], a0B);
          a1A = fmaf(w1, x1[0], a1A); a1B = fmaf(w1, x1[1], a1B);
          a2A = fmaf(w2, x2[0], a2A); a2B = fmaf(w2, x2[1], a2B);
          a3A = fmaf(w3, x3[0], a3A); a3B = fmaf(w3, x3[1], a3B);
        }
      }
      accA[sub * 4 + 0] = a0A; accB[sub * 4 + 0] = a0B;
      accA[sub * 4 + 1] = a1A; accB[sub * 4 + 1] = a1B;
      accA[sub * 4 + 2] = a2A; accB[sub * 4 + 2] = a2B;
      accA[sub * 4 + 3] = a3A; accB[sub * 4 + 3] = a3B;
    }

    // write rows row0+2lane, row0+2lane+1: 128B contiguous per row per group
    float* ypA = y + (size_t)(row0 + 2 * lane) * N_DIM + colbase + g * 32;
    float* ypB = ypA + N_DIM;
#pragma unroll
    for (int q = 0; q < 8; ++q) {
      *(f32x4*)(ypA + q * 4) = (f32x4){accA[q * 4], accA[q * 4 + 1],
                                       accA[q * 4 + 2], accA[q * 4 + 3]};
      *(f32x4*)(ypB + q * 4) = (f32x4){accB[q * 4], accB[q * 4 + 1],
                                       accB[q * 4 + 2], accB[q * 4 + 3]};
    }
  }
}

// ---------- select v5.1: contiguous in-place, 4-chain ballot search ----------
__global__ __launch_bounds__(256) void select_kernel(
    const float* __restrict__ bvec, const float* __restrict__ boost,
    const int* __restrict__ kptr, float* __restrict__ out) {
  const int lane = threadIdx.x & 63;
  const int row = blockIdx.x * 4 + (threadIdx.x >> 6);
  const u32 kk = (u32)kptr[0];
  float* orow = out + (size_t)row * N_DIM;

  u32 kv[64];
#pragma unroll
  for (int v = 0; v < 16; ++v) {
    const int j = v * 256 + lane * 4;              // f32x4, coalesced
    const f32x4 a = *(const f32x4*)(orow + j);
    const f32x4 b = *(const f32x4*)(bvec + j);
    const f32x4 gv = *(const f32x4*)(boost + j);
#pragma unroll
    for (int q = 0; q < 4; ++q) {
      const float yy = a[q] + b[q];                // single f32 add
      const u32 u = __float_as_uint(yy * gv[q]);   // single f32 mult
      kv[v * 4 + q] = (u & 0x80000000u) ? ~u : (u | 0x80000000u);
    }
  }

  // exact k-th-largest key: P = max C with count(key >= C) >= k (ties >=)
  u32 P = 0u;
#pragma unroll 1
  for (int bit = 31; bit >= 0; --bit) {
    const u32 C = P | (1u << bit);
    u32 c0 = 0u, c1 = 0u, c2 = 0u, c3 = 0u;       // 4 indep chains
#pragma unroll
    for (int s = 0; s < 16; ++s) {
      c0 += (u32)__popcll(__ballot(kv[s] >= C));
      c1 += (u32)__popcll(__ballot(kv[s + 16] >= C));
      c2 += (u32)__popcll(__ballot(kv[s + 32] >= C));
      c3 += (u32)__popcll(__ballot(kv[s + 48] >= C));
    }
    const u32 cc = (c0 + c1) + (c2 + c3);
    if (cc >= kk) P = C;                           // uniform
  }

  // re-read (L2-hot), recompute bit-identically, contiguous store
#pragma unroll
  for (int v = 0; v < 16; ++v) {
    const int j = v * 256 + lane * 4;
    const f32x4 a = *(const f32x4*)(orow + j);
    const f32x4 b = *(const f32x4*)(bvec + j);
    const f32x4 gv = *(const f32x4*)(boost + j);
    f32x4 o;
#pragma unroll
    for (int q = 0; q < 4; ++q) {
      const float yy = a[q] + b[q];
      const u32 u = __float_as_uint(yy * gv[q]);
      const u32 key = (u & 0x80000000u) ? ~u : (u | 0x80000000u);
      o[q] = (key >= P) ? yy : 0.0f;
    }
    *(f32x4*)(orow + j) = o;
  }
}

extern "C" void kernel_launch(void* const* d_in, const int* in_sizes, int n_in,
                              void* d_out, int out_size, void* d_ws, size_t ws_size,
                              hipStream_t stream) {
  const float* x     = (const float*)d_in[0];
  const float* W     = (const float*)d_in[1];
  const float* bvec  = (const float*)d_in[2];
  const float* wmask = (const float*)d_in[3];
  const float* duty  = (const float*)d_in[4];
  const int* kptr    = (const int*)d_in[5];
  float* out = (float*)d_out;

  uint8_t* ws = (uint8_t*)d_ws;
  unsigned short* cIdx = (unsigned short*)(ws);                 // 512 KiB
  float* cVal          = (float*)(ws + (1u << 20));             // 1 MiB
  int* cnt             = (int*)(ws + (2u << 20));               // 16 KiB
  float* boost         = (float*)(ws + (2u << 20) + (64u << 10));
  int* cm4             = (int*)(ws + (2u << 20) + (128u << 10)); // 4 KiB
  uint2* pairsA        = (uint2*)(ws + (4u << 20));             // 2 MiB
  float* xTg           = (float*)(ws + (8u << 20));             // 32 MiB
  // ws_size >= 42MB verified on-device in r16 (fold_g path executed).

  boost_kernel<<<16, 256, 0, stream>>>(duty, kptr, boost);
  compress_kernel<<<N_DIM / 4, 256, 0, stream>>>(W, wmask, cIdx, cVal, cnt);
  cmax_kernel<<<4, 256, 0, stream>>>(cnt, cm4);
  fillA_kernel<<<(N_DIM * MAXE) / 256, 256, 0, stream>>>(cIdx, cVal, cnt, pairsA);
  transpose_kernel<<<2048, 256, 0, stream>>>(x, xTg);
  fold_kernel<<<256, 1024, 0, stream>>>(xTg, pairsA, cm4, out);
  select_kernel<<<BATCH / 4, 256, 0, stream>>>(bvec, boost, kptr, out);
}

// Round 12
// 887.527 us; speedup vs baseline: 1.2842x; 1.2842x over previous
//
#include <hip/hip_runtime.h>
#include <stdint.h>
#include <math.h>

// Round 18.
// r17 counters: fold 665us, FETCH 247MB->1.75GB, VALUBusy 15% — 128-row
// blocks made per-XCD gather slices 8MB > 4MB L2 -> L3-path-bound
// (2.15GB/3.25TB/s = 662us, matches). r16's 64-row geometry is load-bearing.
// fold v7 = r16 geometry (64-row blocks, L2-resident 4MB/XCD, FETCH 247MB
// proven) + r17 pair stream (uniform scalar s_loads, low-VALU proven):
// per entry = 1 global_load_dword (saddr=base+e.x, voffset=lane*4) + 1
// v_fmac. Removes r16's 2x readlane + addr VALU tax (67% VALUBusy).
// select v5.1 UNCHANGED -> becomes top dispatch, finally gets counters
// (stable ~435us across 3 variants, unexplained by traffic/VALU models).
// Numerics unchanged (validated): ascending-k f32 fmaf fold from +0
// (zero-pad exact no-op), +bias, *boost, monotone-u32 key, ties >=.

#define BATCH 16384
#define K_DIM 512
#define N_DIM 4096
#define MAXE 64
#define ROWS_A 64

typedef float f32x4 __attribute__((ext_vector_type(4)));
typedef unsigned int u32;

// ---------- boost table ----------
__global__ void boost_kernel(const float* __restrict__ duty,
                             const int* __restrict__ kptr,
                             float* __restrict__ boost) {
  const int j = blockIdx.x * blockDim.x + threadIdx.x;
  if (j < N_DIM) {
    const float td = (float)((double)kptr[0] / (double)N_DIM);
    const float arg = 0.5f * (td - duty[j]);      // f32 ops, as reference
    boost[j] = (float)exp((double)arg);           // correctly-rounded f32 exp
  }
}

// ---------- compress: per-column nonzeros, ascending k ----------
__global__ __launch_bounds__(256) void compress_kernel(
    const float* __restrict__ W, const float* __restrict__ mask,
    unsigned short* __restrict__ cIdx, float* __restrict__ cVal,
    int* __restrict__ cnt) {
  const int j = blockIdx.x * 4 + (threadIdx.x >> 6);  // one wave per column
  const int lane = threadIdx.x & 63;
  if (j >= N_DIM) return;
  const float* mr = mask + (size_t)j * K_DIM;
  const float* wr = W + (size_t)j * K_DIM;
  int base = 0;
#pragma unroll
  for (int c = 0; c < K_DIM / 64; ++c) {
    const int k = c * 64 + lane;
    const bool act = (mr[k] != 0.0f);
    const unsigned long long bal = __ballot(act);
    const int pos = __popcll(bal & ((1ull << lane) - 1ull));
    if (act && base + pos < MAXE) {
      cIdx[(size_t)j * MAXE + base + pos] = (unsigned short)k;
      cVal[(size_t)j * MAXE + base + pos] = wr[k];   // mask==1 -> exact
    }
    base += (int)__popcll(bal);
  }
  if (lane == 0) cnt[j] = base < MAXE ? base : MAXE;
}

// ---------- per-4-col max count, rounded up to 4 ----------
__global__ __launch_bounds__(256) void cmax_kernel(
    const int* __restrict__ cnt, int* __restrict__ cm4) {
  const int i = blockIdx.x * 256 + threadIdx.x;    // 0..1023
  const int4 c = *(const int4*)(cnt + i * 4);
  int m = c.x > c.y ? c.x : c.y;
  m = c.z > m ? c.z : m;
  m = c.w > m ? c.w : m;
  cm4[i] = (m + 3) & ~3;
}

// ---------- pack (xTg byte-offset, w-bits) pairs, zero-padded ----------
__global__ __launch_bounds__(256) void fillA_kernel(
    const unsigned short* __restrict__ cIdx, const float* __restrict__ cVal,
    const int* __restrict__ cnt, uint2* __restrict__ pairsA) {
  const int idx = blockIdx.x * 256 + threadIdx.x;  // 0 .. 4096*64-1
  const int j = idx >> 6;
  const int e = idx & 63;
  uint2 pr;
  if (e < cnt[j]) {
    pr.x = (u32)cIdx[(size_t)j * MAXE + e] << 16;  // k * 16384 rows * 4B
    pr.y = __float_as_uint(cVal[(size_t)j * MAXE + e]);
  } else {
    pr.x = 0u; pr.y = 0u;                          // exact fold no-op
  }
  pairsA[idx] = pr;
}

// ---------- transpose: x[B][K] -> xTg[K][B] ----------
__global__ __launch_bounds__(256) void transpose_kernel(
    const float* __restrict__ x, float* __restrict__ xTg) {
  __shared__ float t[64][65];
  const int lane = threadIdx.x & 63;
  const int quad = threadIdx.x >> 6;               // 0..3
  const int kb = (blockIdx.x & 7) * 64;            // 8 k-tiles
  const int rb = (blockIdx.x >> 3) * 64;           // 256 row-tiles
#pragma unroll
  for (int i = 0; i < 16; ++i) {
    const int r = quad * 16 + i;
    t[lane][r] = x[(size_t)(rb + r) * K_DIM + kb + lane];  // coalesced read
  }
  __syncthreads();
#pragma unroll
  for (int i = 0; i < 16; ++i) {
    const int kq = quad * 16 + i;
    xTg[(size_t)(kb + kq) * BATCH + rb + lane] = t[kq][lane]; // coalesced write
  }
}

// ---------- fold v7: 64-row blocks, scalar pairs, global gather ----------
__global__ __launch_bounds__(1024, 4) void fold_kernel(
    const float* __restrict__ xTg, const uint2* __restrict__ pairsA,
    const int* __restrict__ cm4, float* __restrict__ y) {
  const int tid = threadIdx.x;
  const int lane = tid & 63;
  const int wave = __builtin_amdgcn_readfirstlane(tid >> 6);  // 0..15 uniform
  const int row0 = blockIdx.x * ROWS_A;
  const char* xb = (const char*)(xTg + row0);      // + e.x(byte) + lane*4
  const u32 vb = (u32)(lane << 2);                 // row byte offset

  const int jbase = wave * 256;                    // 256 cols per wave

#pragma unroll 1
  for (int g = 0; g < 8; ++g) {                    // 8 groups of 32 cols
    float acc[32];
#pragma unroll
    for (int q = 0; q < 32; ++q) acc[q] = 0.0f;

#pragma unroll
    for (int sub = 0; sub < 8; ++sub) {            // static: 8 subgrp x 4 cols
      const int j0 = jbase + g * 32 + sub * 4;     // uniform
      const int cmax = cm4[j0 >> 2];               // uniform s_load, mult of 4
      const uint2* p0 = pairsA + (size_t)(j0 + 0) * MAXE;
      const uint2* p1 = pairsA + (size_t)(j0 + 1) * MAXE;
      const uint2* p2 = pairsA + (size_t)(j0 + 2) * MAXE;
      const uint2* p3 = pairsA + (size_t)(j0 + 3) * MAXE;
      float a0 = 0.0f, a1 = 0.0f, a2 = 0.0f, a3 = 0.0f;
#pragma unroll 1
      for (int e = 0; e < cmax; e += 4) {
#pragma unroll
        for (int q = 0; q < 4; ++q) {              // 16 gathers in flight
          const uint2 e0 = p0[e + q];              // uniform -> s_load_dwordx2
          const uint2 e1 = p1[e + q];
          const uint2 e2 = p2[e + q];
          const uint2 e3 = p3[e + q];
          const float x0 = *(const float*)(xb + (e0.x + vb));  // L2-hot
          const float x1 = *(const float*)(xb + (e1.x + vb));
          const float x2 = *(const float*)(xb + (e2.x + vb));
          const float x3 = *(const float*)(xb + (e3.x + vb));
          a0 = fmaf(__uint_as_float(e0.y), x0, a0);  // ascending-k fold
          a1 = fmaf(__uint_as_float(e1.y), x1, a1);
          a2 = fmaf(__uint_as_float(e2.y), x2, a2);
          a3 = fmaf(__uint_as_float(e3.y), x3, a3);
        }
      }
      acc[sub * 4 + 0] = a0;
      acc[sub * 4 + 1] = a1;
      acc[sub * 4 + 2] = a2;
      acc[sub * 4 + 3] = a3;
    }

    // 128B contiguous per lane (= per row) -> full HBM granules
    float* yp = y + (size_t)(row0 + lane) * N_DIM + jbase + g * 32;
#pragma unroll
    for (int q = 0; q < 8; ++q)
      *(f32x4*)(yp + q * 4) =
          (f32x4){acc[q * 4], acc[q * 4 + 1], acc[q * 4 + 2], acc[q * 4 + 3]};
  }
}

// ---------- select v5.1: contiguous in-place, 4-chain ballot search ----------
__global__ __launch_bounds__(256) void select_kernel(
    const float* __restrict__ bvec, const float* __restrict__ boost,
    const int* __restrict__ kptr, float* __restrict__ out) {
  const int lane = threadIdx.x & 63;
  const int row = blockIdx.x * 4 + (threadIdx.x >> 6);
  const u32 kk = (u32)kptr[0];
  float* orow = out + (size_t)row * N_DIM;

  u32 kv[64];
#pragma unroll
  for (int v = 0; v < 16; ++v) {
    const int j = v * 256 + lane * 4;              // f32x4, coalesced
    const f32x4 a = *(const f32x4*)(orow + j);
    const f32x4 b = *(const f32x4*)(bvec + j);
    const f32x4 gv = *(const f32x4*)(boost + j);
#pragma unroll
    for (int q = 0; q < 4; ++q) {
      const float yy = a[q] + b[q];                // single f32 add
      const u32 u = __float_as_uint(yy * gv[q]);   // single f32 mult
      kv[v * 4 + q] = (u & 0x80000000u) ? ~u : (u | 0x80000000u);
    }
  }

  // exact k-th-largest key: P = max C with count(key >= C) >= k (ties >=)
  u32 P = 0u;
#pragma unroll 1
  for (int bit = 31; bit >= 0; --bit) {
    const u32 C = P | (1u << bit);
    u32 c0 = 0u, c1 = 0u, c2 = 0u, c3 = 0u;       // 4 indep chains
#pragma unroll
    for (int s = 0; s < 16; ++s) {
      c0 += (u32)__popcll(__ballot(kv[s] >= C));
      c1 += (u32)__popcll(__ballot(kv[s + 16] >= C));
      c2 += (u32)__popcll(__ballot(kv[s + 32] >= C));
      c3 += (u32)__popcll(__ballot(kv[s + 48] >= C));
    }
    const u32 cc = (c0 + c1) + (c2 + c3);
    if (cc >= kk) P = C;                           // uniform
  }

  // re-read (L2-hot), recompute bit-identically, contiguous store
#pragma unroll
  for (int v = 0; v < 16; ++v) {
    const int j = v * 256 + lane * 4;
    const f32x4 a = *(const f32x4*)(orow + j);
    const f32x4 b = *(const f32x4*)(bvec + j);
    const f32x4 gv = *(const f32x4*)(boost + j);
    f32x4 o;
#pragma unroll
    for (int q = 0; q < 4; ++q) {
      const float yy = a[q] + b[q];
      const u32 u = __float_as_uint(yy * gv[q]);
      const u32 key = (u & 0x80000000u) ? ~u : (u | 0x80000000u);
      o[q] = (key >= P) ? yy : 0.0f;
    }
    *(f32x4*)(orow + j) = o;
  }
}

extern "C" void kernel_launch(void* const* d_in, const int* in_sizes, int n_in,
                              void* d_out, int out_size, void* d_ws, size_t ws_size,
                              hipStream_t stream) {
  const float* x     = (const float*)d_in[0];
  const float* W     = (const float*)d_in[1];
  const float* bvec  = (const float*)d_in[2];
  const float* wmask = (const float*)d_in[3];
  const float* duty  = (const float*)d_in[4];
  const int* kptr    = (const int*)d_in[5];
  float* out = (float*)d_out;

  uint8_t* ws = (uint8_t*)d_ws;
  unsigned short* cIdx = (unsigned short*)(ws);                 // 512 KiB
  float* cVal          = (float*)(ws + (1u << 20));             // 1 MiB
  int* cnt             = (int*)(ws + (2u << 20));               // 16 KiB
  float* boost         = (float*)(ws + (2u << 20) + (64u << 10));
  int* cm4             = (int*)(ws + (2u << 20) + (128u << 10)); // 4 KiB
  uint2* pairsA        = (uint2*)(ws + (4u << 20));             // 2 MiB
  float* xTg           = (float*)(ws + (8u << 20));             // 32 MiB
  // ws_size >= 42MB verified on-device (r16 fold_g path executed).

  boost_kernel<<<16, 256, 0, stream>>>(duty, kptr, boost);
  compress_kernel<<<N_DIM / 4, 256, 0, stream>>>(W, wmask, cIdx, cVal, cnt);
  cmax_kernel<<<4, 256, 0, stream>>>(cnt, cm4);
  fillA_kernel<<<(N_DIM * MAXE) / 256, 256, 0, stream>>>(cIdx, cVal, cnt, pairsA);
  transpose_kernel<<<2048, 256, 0, stream>>>(x, xTg);
  fold_kernel<<<BATCH / ROWS_A, 1024, 0, stream>>>(xTg, pairsA, cm4, out);
  select_kernel<<<BATCH / 4, 256, 0, stream>>>(bvec, boost, kptr, out);
}